// Round 8
// baseline (736.942 us; speedup 1.0000x reference)
//
#include <hip/hip_runtime.h>
#include <hip/hip_fp16.h>
#include <math.h>

// Problem constants (fixed by reference setup_inputs)
#define BB 4096
#define LL 16
#define DD 512

#define LOG2E_F  1.4426950408889634f
#define LN2_F    0.6931471805599453f
#define LOG2PI_F 1.8378770664093453f

// f16-Schraudolph via pknorm: coefs scaled by S=1024/65535 with offset OFFC
// folded in. pknorm_u16(lp_n) = round(1024*(lp2+OFFC)) = f16 bits of
// 2^(lp2 + OFFC-15) (OFFC=23 -> 2^(lp2+8)); negatives clamp to 0.
#define OFFC     22.942540f
#define SCALE23  8388608.0f
#define BIASF    126.94269504f

#if __has_builtin(__builtin_amdgcn_exp2f)
#define EXP2(x) __builtin_amdgcn_exp2f(x)
#else
#define EXP2(x) exp2f(x)
#endif
#if __has_builtin(__builtin_amdgcn_logf)
#define LOG2(x) __builtin_amdgcn_logf(x)
#else
#define LOG2(x) log2f(x)
#endif

// ws float layout:
//   coef    [0      , 196608)   4096 j * 48  (A''[16] B''[16] C''[16], S-scaled)
//   rp      [196608 , 198656)   2048 recon block partials (pre-scaled)
//   klp     [198656 , 198912)   256 KL block partials (pre-scaled)
//   partial [268544 , +nc*9*4096)  packed tc partials (8 f16-pair words + joint)
//   red2    [.. , +G*17*BB)        group sums (G = nc/16), k-major
//   scratch [.. , +nc*9*BB)        ablation dump (never read)
#define COEF_F   0
#define RP_F     196608
#define KLP_F    198656
#define PART_F   268544

enum { V_FULL = 0, V_NOLDS = 1, V_LDSONLY = 2, V_NOMARG = 3, V_NOJOINT = 4 };

// Block-level sum reduction; result valid on thread 0. Re-entrant.
__device__ __forceinline__ float block_reduce(float v) {
  __shared__ float sm[4];
  __syncthreads();
#pragma unroll
  for (int off = 32; off; off >>= 1) v += __shfl_xor(v, off);
  if ((threadIdx.x & 63) == 0) sm[threadIdx.x >> 6] = v;
  __syncthreads();
  if (threadIdx.x == 0) v = (sm[0] + sm[1]) + (sm[2] + sm[3]);
  return v;
}

// ---------------------------------------------------------------------------
// Kernel A: recon partials + coef prep + KL partials + out zero. (unchanged)
// ---------------------------------------------------------------------------
__global__ __launch_bounds__(256) void prep_recon_kernel(
    const float4* __restrict__ data4, const float4* __restrict__ recon4,
    const float* __restrict__ zm, const float* __restrict__ zlv,
    float* __restrict__ coef, float* __restrict__ rp,
    float* __restrict__ klp, float* __restrict__ out) {
  const int tid = threadIdx.x;
  const int b = blockIdx.x;

  if (b == 1024 && tid == 0) out[0] = 0.0f;

  {
    const int n4 = (BB * DD) / 4;
    int stride = gridDim.x * 256;
    float s = 0.0f;
    for (int k = b * 256 + tid; k < n4; k += stride) {
      float4 a = data4[k];
      float4 r = recon4[k];
      s += (fabsf(a.x - r.x) + fabsf(a.y - r.y)) +
           (fabsf(a.z - r.z) + fabsf(a.w - r.w));
    }
    float t = block_reduce(s);
    if (tid == 0) rp[b] = t * (1.0f / (float)(BB * DD));
  }

  if (b < 256) {
    const float S = 1024.0f / 65535.0f;
    int idx = b * 256 + tid;
    int j = idx >> 4;
    int l = idx & 15;
    float m = zm[idx];
    float lv = zlv[idx];
    float inv = EXP2(-lv * LOG2E_F);
    float a = -0.5f * LOG2E_F * inv;
    float c2 = -0.5f * LOG2E_F * (lv + LOG2PI_F);
    coef[j * 48 + l]      = a * S;
    coef[j * 48 + 16 + l] = -2.0f * a * m * S;
    coef[j * 48 + 32 + l] = (fmaf(a, m * m, c2) + OFFC) * S;

    float kls = m * m + EXP2(lv * LOG2E_F) - lv - 1.0f;
    float s = block_reduce(kls);
    if (tid == 0) klp[b] = s * (0.5f / (float)BB);
  }
}

// ---------------------------------------------------------------------------
// TC body (R5 structure: CHUNK=16, R=4, LDS coef, barrier, pinned zv).
// ABLATION INSTRUMENTED: template VAR stubs out one phase at a time with
// asm keep-alives (rule #17: ablation-via-skip must keep upstream values
// live). REP repeats the j-loop; opaque per-iteration pins (on the LDS
// offset, or the reg-coefs for NOLDS) defeat cross-rep CSE so each rep
// re-issues the full load+compute stream.
// ---------------------------------------------------------------------------
template <int CHUNK, int R, int VAR, int REP>
__device__ __forceinline__ void tc_body(
    const float* __restrict__ z, const float* __restrict__ coef,
    float* __restrict__ partial) {
  __shared__ float lcoef[CHUNK * 48];
  const int tid = threadIdx.x;
  const int i0 = blockIdx.x * (256 * R) + tid;
  const int j0 = blockIdx.y * CHUNK;
  const float JMUL = 65535.0f * 8192.0f;
  const float JK   = -SCALE23 * (16.0f * OFFC - BIASF);

  {
    const float4* g4 = (const float4*)(coef + (size_t)j0 * 48);
    float4* l4 = (float4*)lcoef;
    for (int t = tid; t < (CHUNK * 48) / 4; t += 256) l4[t] = g4[t];
  }

  float zv[R][16];
#pragma unroll
  for (int r = 0; r < R; ++r) {
    const float4* zp = (const float4*)(z + (size_t)(i0 + 256 * r) * 16);
#pragma unroll
    for (int q = 0; q < 4; ++q) {
      float4 v = zp[q];
      zv[r][4 * q] = v.x; zv[r][4 * q + 1] = v.y;
      zv[r][4 * q + 2] = v.z; zv[r][4 * q + 3] = v.w;
    }
  }
#pragma unroll
  for (int r = 0; r < R; ++r)
#pragma unroll
    for (int p = 0; p < 16; ++p) asm volatile("" : "+v"(zv[r][p]));

  // NOLDS: one q-slab of coefs held in VGPRs (reused all q,j) -> same compute
  // instruction count, zero ds_read in the loop.
  float rc[12];
  if (VAR == V_NOLDS) {
#pragma unroll
    for (int t = 0; t < 12; ++t)
      rc[t] = coef[(size_t)j0 * 48 + (size_t)(t >> 2) * 16 + (t & 3)];
#pragma unroll
    for (int t = 0; t < 12; ++t) asm volatile("" : "+v"(rc[t]));
  }

  union HU { unsigned u; __half2 h; };
  __half2 accH[R][8];
#pragma unroll
  for (int r = 0; r < R; ++r)
#pragma unroll
    for (int p = 0; p < 8; ++p) { HU t; t.u = 0u; accH[r][p] = t.h; }
  float accJ[R];
#pragma unroll
  for (int r = 0; r < R; ++r) accJ[r] = 0.0f;

  __syncthreads();

  for (int jt = 0; jt < CHUNK * REP; ++jt) {
    unsigned off = (unsigned)(jt & (CHUNK - 1)) * 192u;
    if (VAR != V_NOLDS) {
      asm volatile("" : "+v"(off));  // opaque addr: defeat cross-rep CSE
    } else {
#pragma unroll
      for (int t = 0; t < 12; ++t) asm volatile("" : "+v"(rc[t]));
    }
    const float* cp = (const float*)((const char*)lcoef + off);
    float js[R];
#pragma unroll
    for (int r = 0; r < R; ++r) js[r] = 0.0f;

#pragma unroll
    for (int q = 0; q < 4; ++q) {
      float4 va, vb, vc;
      if (VAR == V_NOLDS) {
        va = make_float4(rc[0], rc[1], rc[2], rc[3]);
        vb = make_float4(rc[4], rc[5], rc[6], rc[7]);
        vc = make_float4(rc[8], rc[9], rc[10], rc[11]);
      } else {
        va = *(const float4*)(cp + 4 * q);
        vb = *(const float4*)(cp + 16 + 4 * q);
        vc = *(const float4*)(cp + 32 + 4 * q);
      }
      if (VAR == V_LDSONLY) {
        asm volatile("" :: "v"(va.x), "v"(va.y), "v"(va.z), "v"(va.w));
        asm volatile("" :: "v"(vb.x), "v"(vb.y), "v"(vb.z), "v"(vb.w));
        asm volatile("" :: "v"(vc.x), "v"(vc.y), "v"(vc.z), "v"(vc.w));
        continue;
      }
#pragma unroll
      for (int r = 0; r < R; ++r) {
        float lp0 = fmaf(fmaf(va.x, zv[r][4 * q + 0], vb.x), zv[r][4 * q + 0], vc.x);
        float lp1 = fmaf(fmaf(va.y, zv[r][4 * q + 1], vb.y), zv[r][4 * q + 1], vc.y);
        float lp2 = fmaf(fmaf(va.z, zv[r][4 * q + 2], vb.z), zv[r][4 * q + 2], vc.z);
        float lp3 = fmaf(fmaf(va.w, zv[r][4 * q + 3], vb.w), zv[r][4 * q + 3], vc.w);
        if (VAR != V_NOMARG) {
          HU h0, h1;
          asm("v_cvt_pknorm_u16_f32 %0, %1, %2"
              : "=v"(h0.u) : "v"(lp0), "v"(lp1));
          asm("v_cvt_pknorm_u16_f32 %0, %1, %2"
              : "=v"(h1.u) : "v"(lp2), "v"(lp3));
          accH[r][2 * q]     = __hadd2(accH[r][2 * q], h0.h);
          accH[r][2 * q + 1] = __hadd2(accH[r][2 * q + 1], h1.h);
        }
        if (VAR != V_NOJOINT) js[r] += (lp0 + lp1) + (lp2 + lp3);
        if (VAR == V_NOMARG && VAR == V_NOJOINT) {
          // unreachable; lp kept live by one of the two paths above
        }
      }
    }
    if (VAR != V_NOJOINT && VAR != V_LDSONLY) {
#pragma unroll
      for (int r = 0; r < R; ++r) {
        float w = fmaf(js[r], JMUL, JK);
        unsigned u;
        asm("v_cvt_u32_f32 %0, %1" : "=v"(u) : "v"(w));
        accJ[r] += __uint_as_float(u);
      }
    }
  }

#pragma unroll
  for (int r = 0; r < R; ++r) {
    const size_t b9 = ((size_t)blockIdx.y * 9) * BB + (size_t)(i0 + 256 * r);
    unsigned* up = (unsigned*)partial;
#pragma unroll
    for (int p = 0; p < 8; ++p) {
      HU t; t.h = accH[r][p];
      up[b9 + (size_t)p * BB] = t.u;
    }
    partial[b9 + (size_t)8 * BB] = accJ[r];
  }
}

// Distinctly-named instantiations so rocprof rows are identifiable.
__global__ __launch_bounds__(256, 3) void tc_full6(
    const float* __restrict__ z, const float* __restrict__ c, float* __restrict__ p) {
  tc_body<16, 4, V_FULL, 6>(z, c, p);
}
__global__ __launch_bounds__(256, 3) void tc_nolds6(
    const float* __restrict__ z, const float* __restrict__ c, float* __restrict__ p) {
  tc_body<16, 4, V_NOLDS, 6>(z, c, p);
}
__global__ __launch_bounds__(256, 3) void tc_lds10(
    const float* __restrict__ z, const float* __restrict__ c, float* __restrict__ p) {
  tc_body<16, 4, V_LDSONLY, 10>(z, c, p);
}
__global__ __launch_bounds__(256, 3) void tc_nomarg6(
    const float* __restrict__ z, const float* __restrict__ c, float* __restrict__ p) {
  tc_body<16, 4, V_NOMARG, 6>(z, c, p);
}
__global__ __launch_bounds__(256, 3) void tc_nojoint6(
    const float* __restrict__ z, const float* __restrict__ c, float* __restrict__ p) {
  tc_body<16, 4, V_NOJOINT, 6>(z, c, p);
}
__global__ __launch_bounds__(256, 3) void tc_real(
    const float* __restrict__ z, const float* __restrict__ c, float* __restrict__ p) {
  tc_body<16, 4, V_FULL, 1>(z, c, p);
}
__global__ __launch_bounds__(256, 3) void tc_real32(
    const float* __restrict__ z, const float* __restrict__ c, float* __restrict__ p) {
  tc_body<32, 4, V_FULL, 1>(z, c, p);
}

// ---------------------------------------------------------------------------
// Kernel C: group-reduce packed partials. grid (16, G), G = nc/16. (unchanged)
// ---------------------------------------------------------------------------
__global__ __launch_bounds__(256) void reduce_kernel(
    const unsigned* __restrict__ partial, float* __restrict__ red2) {
  const int i = blockIdx.x * 256 + threadIdx.x;
  const int g = blockIdx.y;
  const unsigned* p = partial + ((size_t)g * 16 * 9) * BB + i;

  float s[17];
#pragma unroll
  for (int k = 0; k < 17; ++k) s[k] = 0.0f;

#pragma unroll 4
  for (int c = 0; c < 16; ++c) {
    const size_t cb = (size_t)c * 9 * BB;
    union HU { unsigned u; __half2 h; };
#pragma unroll
    for (int q = 0; q < 8; ++q) {
      HU t; t.u = p[cb + (size_t)q * BB];
      s[2 * q]     += __low2float(t.h);
      s[2 * q + 1] += __high2float(t.h);
    }
    s[16] += __uint_as_float(p[cb + (size_t)8 * BB]);
  }

  float* r2 = red2 + ((size_t)g * 17) * BB + i;
#pragma unroll
  for (int k = 0; k < 16; ++k)
    r2[(size_t)k * BB] = s[k] * 0.00390625f;
  r2[(size_t)16 * BB] = s[16];
}

// ---------------------------------------------------------------------------
// Kernel D: sum G group-planes, logs, fold recon/KL into out[0]. (unchanged)
// ---------------------------------------------------------------------------
__global__ __launch_bounds__(256) void final_kernel(
    const float* __restrict__ red2, const float* __restrict__ rp,
    const float* __restrict__ klp, float* __restrict__ out, int G) {
  const int tid = threadIdx.x;
  const int i = blockIdx.x * 256 + tid;

  float acc[17];
#pragma unroll
  for (int k = 0; k < 17; ++k) acc[k] = 0.0f;
  for (int g = 0; g < G; ++g) {
    const float* r2 = red2 + ((size_t)g * 17) * BB + i;
#pragma unroll
    for (int k = 0; k < 17; ++k) acc[k] += r2[(size_t)k * BB];
  }

  float lg = LOG2(acc[16]);
#pragma unroll
  for (int k = 0; k < 16; ++k) lg -= LOG2(acc[k]);
  float t = lg * (LN2_F / (float)BB);
  if (blockIdx.x == 0) {
#pragma unroll
    for (int q = 0; q < 8; ++q) t += rp[tid + 256 * q];
    t += klp[tid];
  }
  float s = block_reduce(t);
  if (tid == 0) atomicAdd(out, s);
}

extern "C" void kernel_launch(void* const* d_in, const int* in_sizes, int n_in,
                              void* d_out, int out_size, void* d_ws, size_t ws_size,
                              hipStream_t stream) {
  const float* data  = (const float*)d_in[0];
  const float* recon = (const float*)d_in[1];
  const float* z     = (const float*)d_in[2];
  const float* zm    = (const float*)d_in[3];
  const float* zlv   = (const float*)d_in[4];
  float* out = (float*)d_out;
  float* ws  = (float*)d_ws;

  int nc = 256;
  {
    size_t need = (size_t)PART_F + 2 * (size_t)nc * 9 * BB + (size_t)(nc / 16) * 17 * BB;
    if (need * 4 > ws_size) nc = 128;
  }
  const int G = nc / 16;

  float* coef = ws + COEF_F;
  float* rp   = ws + RP_F;
  float* klp  = ws + KLP_F;
  float* part = ws + PART_F;
  float* red2 = ws + PART_F + (size_t)nc * 9 * BB;
  float* scr  = red2 + (size_t)G * 17 * BB;  // ablation dump, never read

  hipLaunchKernelGGL(prep_recon_kernel, dim3(2048), dim3(256), 0, stream,
                     reinterpret_cast<const float4*>(data),
                     reinterpret_cast<const float4*>(recon),
                     zm, zlv, coef, rp, klp, out);
  if (nc == 256) {
    // --- ablation dispatches (scratch output; read per-dispatch dur_us) ---
    hipLaunchKernelGGL(tc_full6,    dim3(4, 256), dim3(256), 0, stream, z, coef, scr);
    hipLaunchKernelGGL(tc_nolds6,   dim3(4, 256), dim3(256), 0, stream, z, coef, scr);
    hipLaunchKernelGGL(tc_lds10,    dim3(4, 256), dim3(256), 0, stream, z, coef, scr);
    hipLaunchKernelGGL(tc_nomarg6,  dim3(4, 256), dim3(256), 0, stream, z, coef, scr);
    hipLaunchKernelGGL(tc_nojoint6, dim3(4, 256), dim3(256), 0, stream, z, coef, scr);
    // --- real pipeline ---
    hipLaunchKernelGGL(tc_real,     dim3(4, 256), dim3(256), 0, stream, z, coef, part);
  } else {
    hipLaunchKernelGGL(tc_real32,   dim3(4, 128), dim3(256), 0, stream, z, coef, part);
  }
  hipLaunchKernelGGL(reduce_kernel, dim3(BB / 256, G), dim3(256), 0, stream,
                     reinterpret_cast<const unsigned*>(part), red2);
  hipLaunchKernelGGL(final_kernel, dim3(BB / 256), dim3(256), 0, stream,
                     red2, rp, klp, out, G);
}

// Round 10
// 116.791 us; speedup vs baseline: 6.3099x; 6.3099x over previous
//
#include <hip/hip_runtime.h>
#include <hip/hip_fp16.h>
#include <math.h>

// Problem constants (fixed by reference setup_inputs)
#define BB 4096
#define LL 16
#define DD 512

#define LOG2E_F  1.4426950408889634f
#define LN2_F    0.6931471805599453f
#define LOG2PI_F 1.8378770664093453f

// f16-Schraudolph via pknorm: coefs scaled by S=1024/65535 with offset OFFC
// folded in. pknorm_u16(lp_n) = round(1024*(lp2+OFFC)) = f16 bits of
// 2^(lp2 + OFFC-15) (OFFC=23 -> 2^(lp2+8)); negatives clamp to 0.
#define OFFC     22.942540f
#define SCALE23  8388608.0f
#define BIASF    126.94269504f

#if __has_builtin(__builtin_amdgcn_exp2f)
#define EXP2(x) __builtin_amdgcn_exp2f(x)
#else
#define EXP2(x) exp2f(x)
#endif
#if __has_builtin(__builtin_amdgcn_logf)
#define LOG2(x) __builtin_amdgcn_logf(x)
#else
#define LOG2(x) log2f(x)
#endif

typedef float f32x2 __attribute__((ext_vector_type(2)));

// ws float layout (nc = 128):
//   coef    [0      , 196608)   4096 j * 48  (A[16] B[16] C[16], S-scaled)
//   rp      [196608 , 198656)   2048 recon block partials (pre-scaled)
//   klp     [198656 , 198912)   256 KL block partials (pre-scaled)
//   partial [268544 , +nc*9*4096)  packed tc partials (8 f16-pair words + joint)
//   red2    [.. , +G*17*BB)        group sums (G = nc/16), k-major
#define COEF_F   0
#define RP_F     196608
#define KLP_F    198656
#define PART_F   268544

// Block-level sum reduction; result valid on thread 0. Re-entrant.
__device__ __forceinline__ float block_reduce(float v) {
  __shared__ float sm[4];
  __syncthreads();
#pragma unroll
  for (int off = 32; off; off >>= 1) v += __shfl_xor(v, off);
  if ((threadIdx.x & 63) == 0) sm[threadIdx.x >> 6] = v;
  __syncthreads();
  if (threadIdx.x == 0) v = (sm[0] + sm[1]) + (sm[2] + sm[3]);
  return v;
}

// ---------------------------------------------------------------------------
// Kernel A: recon partials + coef prep + KL partials + out zero.
// Expanded-quadratic coefs: lp' = (A*z + B)*z + C = S*(lp2 + OFFC)
// ---------------------------------------------------------------------------
__global__ __launch_bounds__(256) void prep_recon_kernel(
    const float4* __restrict__ data4, const float4* __restrict__ recon4,
    const float* __restrict__ zm, const float* __restrict__ zlv,
    float* __restrict__ coef, float* __restrict__ rp,
    float* __restrict__ klp, float* __restrict__ out) {
  const int tid = threadIdx.x;
  const int b = blockIdx.x;

  if (b == 1024 && tid == 0) out[0] = 0.0f;

  {
    const int n4 = (BB * DD) / 4;
    int stride = gridDim.x * 256;
    float s = 0.0f;
    for (int k = b * 256 + tid; k < n4; k += stride) {
      float4 a = data4[k];
      float4 r = recon4[k];
      s += (fabsf(a.x - r.x) + fabsf(a.y - r.y)) +
           (fabsf(a.z - r.z) + fabsf(a.w - r.w));
    }
    float t = block_reduce(s);
    if (tid == 0) rp[b] = t * (1.0f / (float)(BB * DD));
  }

  if (b < 256) {
    const float S = 1024.0f / 65535.0f;
    int idx = b * 256 + tid;
    int j = idx >> 4;
    int l = idx & 15;
    float m = zm[idx];
    float lv = zlv[idx];
    float inv = EXP2(-lv * LOG2E_F);
    float a = -0.5f * LOG2E_F * inv;
    float c2 = -0.5f * LOG2E_F * (lv + LOG2PI_F);
    coef[j * 48 + l]      = a * S;                            // A
    coef[j * 48 + 16 + l] = -2.0f * a * m * S;                // B
    coef[j * 48 + 32 + l] = (fmaf(a, m * m, c2) + OFFC) * S;  // C

    float kls = m * m + EXP2(lv * LOG2E_F) - lv - 1.0f;
    float s = block_reduce(kls);
    if (tid == 0) klp[b] = s * (0.5f / (float)BB);
  }
}

// One j's coefs as 24 f32 pairs: A pairs [0..8), B [8..16), C [16..24).
struct C48 { f32x2 v[24]; };

__device__ __forceinline__ void ldcoef(C48& b, const float* cp) {
#pragma unroll
  for (int t = 0; t < 12; ++t)  // 12x ds_read_b128
    *(float4*)&b.v[2 * t] = *(const float4*)(cp + 4 * t);
}

union HU { unsigned u; __half2 h; };

// ---------------------------------------------------------------------------
// Kernel B: TC partial sums. R=4 rows/thread, CHUNK=32, packed VOP3P math,
// EXPLICIT double-buffered coef prefetch.
// R8 ablation: j-loop = 31.75us/pass + ~12us fixed overhead = 44us real.
// R5 (packed, -20% instr) showed NO gain -> binder is exposed LDS, not VALU
// count. R0-validated model: LDS return bus delivers 1KB/instr regardless of
// broadcast; coef delivery 192B/lane/j is invariant; only R divides it
// (R=4 -> 15.4us floor). Compiler never pipelined (VGPR 76-80 = serialized
// fetch->compute per j). Fixes:
//  1. Named even/odd C48 buffers; issue j+1's 12 ds_read_b128 BEFORE
//     computing j -> ~120cy LDS latency hides under ~360cy compute.
//     (256,2) gives VGPR headroom (~220 needed: zv 64 + bufs 96 + acc 36).
//  2. Packed expanded poly (2 v_pk_fma/pair): ~180 instr/j -> VALU ~10us,
//     safely under the LDS floor.
//  3. CHUNK=32/nc=128: halves partial-store traffic (37.7->18.9 MB).
// Grid (4, 128) = 512 blocks = 2 blocks/CU (R4 validated this shape).
// ---------------------------------------------------------------------------
template <int CHUNK, int R>
__device__ __forceinline__ void jbody(
    const C48& cb, const f32x2 zv[R][8], __half2 accH[R][8], float accJ[R],
    float JMUL, float JK) {
  f32x2 js2[R];
#pragma unroll
  for (int r = 0; r < R; ++r) js2[r] = (f32x2){0.0f, 0.0f};
#pragma unroll
  for (int p = 0; p < 8; ++p) {
#pragma unroll
    for (int r = 0; r < R; ++r) {
      f32x2 lp = __builtin_elementwise_fma(
          __builtin_elementwise_fma(cb.v[p], zv[r][p], cb.v[8 + p]),
          zv[r][p], cb.v[16 + p]);                     // 2x v_pk_fma_f32
      HU h;
      asm("v_cvt_pknorm_u16_f32 %0, %1, %2"
          : "=v"(h.u) : "v"(lp.x), "v"(lp.y));
      accH[r][p] = __hadd2(accH[r][p], h.h);
      js2[r] += lp;                                    // v_pk_add_f32
    }
  }
#pragma unroll
  for (int r = 0; r < R; ++r) {
    float w = fmaf(js2[r].x + js2[r].y, JMUL, JK);
    unsigned u;
    asm("v_cvt_u32_f32 %0, %1" : "=v"(u) : "v"(w));    // neg saturates to 0
    accJ[r] += __uint_as_float(u);
  }
}

template <int CHUNK, int R>
__global__ __launch_bounds__(256, 2) void tc_kernel(
    const float* __restrict__ z, const float* __restrict__ coef,
    float* __restrict__ partial) {
  __shared__ float lcoef[CHUNK * 48];
  const int tid = threadIdx.x;
  const int i0 = blockIdx.x * (256 * R) + tid;
  const int j0 = blockIdx.y * CHUNK;
  const float JMUL = 65535.0f * 8192.0f;
  const float JK   = -SCALE23 * (16.0f * OFFC - BIASF);

  // Stage this block's coef chunk into LDS (coalesced float4 loads).
  {
    const float4* g4 = (const float4*)(coef + (size_t)j0 * 48);
    float4* l4 = (float4*)lcoef;
    for (int t = tid; t < (CHUNK * 48) / 4; t += 256) l4[t] = g4[t];
  }

  // z rows in registers as 8 f32 pairs per row; pinned (R4: compiler
  // otherwise sinks these loads into the j-loop).
  f32x2 zv[R][8];
#pragma unroll
  for (int r = 0; r < R; ++r) {
    const float4* zp = (const float4*)(z + (size_t)(i0 + 256 * r) * 16);
#pragma unroll
    for (int q = 0; q < 4; ++q) {
      float4 v = zp[q];
      zv[r][2 * q]     = (f32x2){v.x, v.y};
      zv[r][2 * q + 1] = (f32x2){v.z, v.w};
    }
  }
#pragma unroll
  for (int r = 0; r < R; ++r)
#pragma unroll
    for (int p = 0; p < 8; ++p) asm volatile("" : "+v"(zv[r][p]));

  __half2 accH[R][8];
#pragma unroll
  for (int r = 0; r < R; ++r)
#pragma unroll
    for (int p = 0; p < 8; ++p) { HU t; t.u = 0u; accH[r][p] = t.h; }
  float accJ[R];
#pragma unroll
  for (int r = 0; r < R; ++r) accJ[r] = 0.0f;

  __syncthreads();

  // Software-pipelined j-loop: named even/odd buffers, prefetch j+1 before
  // computing j. Wrap via mask (harmless re-read of row 0 at the tail).
  C48 bA, bB;
  ldcoef(bA, lcoef);
#pragma unroll 1
  for (int j = 0; j < CHUNK; j += 2) {
    ldcoef(bB, lcoef + ((j + 1) & (CHUNK - 1)) * 48);
    jbody<CHUNK, R>(bA, zv, accH, accJ, JMUL, JK);
    ldcoef(bA, lcoef + ((j + 2) & (CHUNK - 1)) * 48);
    jbody<CHUNK, R>(bB, zv, accH, accJ, JMUL, JK);
  }

  // Packed store: 8 raw f16-pair words + 1 f32 joint per (i, chunk).
#pragma unroll
  for (int r = 0; r < R; ++r) {
    const size_t b9 = ((size_t)blockIdx.y * 9) * BB + (size_t)(i0 + 256 * r);
    unsigned* up = (unsigned*)partial;
#pragma unroll
    for (int p = 0; p < 8; ++p) {
      HU t; t.h = accH[r][p];
      up[b9 + (size_t)p * BB] = t.u;
    }
    partial[b9 + (size_t)8 * BB] = accJ[r];
  }
}

// ---------------------------------------------------------------------------
// Kernel C: group-reduce packed partials. grid (16, G), G = nc/16; each block
// sums a 16-chunk group for 256 i's, unpacking f16 pairs -> 17 f32 planes.
// ---------------------------------------------------------------------------
__global__ __launch_bounds__(256) void reduce_kernel(
    const unsigned* __restrict__ partial, float* __restrict__ red2) {
  const int i = blockIdx.x * 256 + threadIdx.x;
  const int g = blockIdx.y;
  const unsigned* p = partial + ((size_t)g * 16 * 9) * BB + i;

  float s[17];
#pragma unroll
  for (int k = 0; k < 17; ++k) s[k] = 0.0f;

#pragma unroll 4
  for (int c = 0; c < 16; ++c) {
    const size_t cb = (size_t)c * 9 * BB;
#pragma unroll
    for (int q = 0; q < 8; ++q) {
      HU t; t.u = p[cb + (size_t)q * BB];
      s[2 * q]     += __low2float(t.h);
      s[2 * q + 1] += __high2float(t.h);
    }
    s[16] += __uint_as_float(p[cb + (size_t)8 * BB]);
  }

  float* r2 = red2 + ((size_t)g * 17) * BB + i;
#pragma unroll
  for (int k = 0; k < 16; ++k)
    r2[(size_t)k * BB] = s[k] * 0.00390625f;  // 2^-8 rescale to true exp2 sums
  r2[(size_t)16 * BB] = s[16];
}

// ---------------------------------------------------------------------------
// Kernel D: sum G group-planes, logs, fold recon/KL into out[0].
// ---------------------------------------------------------------------------
__global__ __launch_bounds__(256) void final_kernel(
    const float* __restrict__ red2, const float* __restrict__ rp,
    const float* __restrict__ klp, float* __restrict__ out, int G) {
  const int tid = threadIdx.x;
  const int i = blockIdx.x * 256 + tid;

  float acc[17];
#pragma unroll
  for (int k = 0; k < 17; ++k) acc[k] = 0.0f;
  for (int g = 0; g < G; ++g) {
    const float* r2 = red2 + ((size_t)g * 17) * BB + i;
#pragma unroll
    for (int k = 0; k < 17; ++k) acc[k] += r2[(size_t)k * BB];
  }

  float lg = LOG2(acc[16]);  // log2 S_joint
#pragma unroll
  for (int k = 0; k < 16; ++k) lg -= LOG2(acc[k]);
  float t = lg * (LN2_F / (float)BB);
  if (blockIdx.x == 0) {
#pragma unroll
    for (int q = 0; q < 8; ++q) t += rp[tid + 256 * q];
    t += klp[tid];
  }
  float s = block_reduce(t);
  if (tid == 0) atomicAdd(out, s);
}

extern "C" void kernel_launch(void* const* d_in, const int* in_sizes, int n_in,
                              void* d_out, int out_size, void* d_ws, size_t ws_size,
                              hipStream_t stream) {
  const float* data  = (const float*)d_in[0];
  const float* recon = (const float*)d_in[1];
  const float* z     = (const float*)d_in[2];
  const float* zm    = (const float*)d_in[3];
  const float* zlv   = (const float*)d_in[4];
  float* out = (float*)d_out;
  float* ws  = (float*)d_ws;

  const int nc = 128;  // CHUNK=32, grid (4,128) = 512 blocks = 2/CU
  const int G = nc / 16;

  float* coef = ws + COEF_F;
  float* rp   = ws + RP_F;
  float* klp  = ws + KLP_F;
  float* part = ws + PART_F;
  float* red2 = ws + PART_F + (size_t)nc * 9 * BB;

  hipLaunchKernelGGL(prep_recon_kernel, dim3(2048), dim3(256), 0, stream,
                     reinterpret_cast<const float4*>(data),
                     reinterpret_cast<const float4*>(recon),
                     zm, zlv, coef, rp, klp, out);
  hipLaunchKernelGGL((tc_kernel<32, 4>), dim3(4, 128), dim3(256), 0, stream,
                     z, coef, part);
  hipLaunchKernelGGL(reduce_kernel, dim3(BB / 256, G), dim3(256), 0, stream,
                     reinterpret_cast<const unsigned*>(part), red2);
  hipLaunchKernelGGL(final_kernel, dim3(BB / 256), dim3(256), 0, stream,
                     red2, rp, klp, out, G);
}